// Round 1
// baseline (533.187 us; speedup 1.0000x reference)
//
#include <hip/hip_runtime.h>
#include <stdint.h>

#define N 8192
#define FEAT 256
#define HID 64
#define ALPHA 0.2f
#define SBOUND 16.0f
#define LOG2E 1.44269504088896f

typedef __attribute__((ext_vector_type(8))) short short8;
typedef __attribute__((ext_vector_type(4))) float floatx4;

static __device__ __forceinline__ unsigned short f32_to_bf16(float f) {
    union { float f; unsigned int u; } c; c.f = f;
    unsigned int u = c.u;
    unsigned int r = u + 0x7FFFu + ((u >> 16) & 1u);  // RNE
    return (unsigned short)(r >> 16);
}

// ---------------------------------------------------------------------------
// Kernel 1: h = inputs@W (fp32), s_src = h@a[:H], s_dst = h@a[H:],
// hfrag = bf16(h) pre-swizzled into MFMA 16x16x32 B-fragment order.
// Also zero-initializes acc_g and l_acc (ws is poisoned 0xAA each call).
// Block = 256 thr (4 waves), 16 rows/block, grid = 512.
// ---------------------------------------------------------------------------
__global__ __launch_bounds__(256) void k1_prep(
    const float* __restrict__ inputs, const float* __restrict__ W,
    const float* __restrict__ a,
    float* __restrict__ s_src, float* __restrict__ s_dst,
    unsigned short* __restrict__ hfrag, float* __restrict__ acc_zero)
{
    __shared__ float inlds[16 * FEAT];  // 16 KB
    const int t = threadIdx.x;
    const int rb = blockIdx.x * 16;

    // zero acc_g (N*HID) + l_acc (N) = 532480 floats = 133120 float4
    {
        const int totf4 = (N * HID + N) / 4;
        float4 z = make_float4(0.f, 0.f, 0.f, 0.f);
        for (int i = blockIdx.x * 256 + t; i < totf4; i += gridDim.x * 256)
            ((float4*)acc_zero)[i] = z;
    }

    // stage 16 input rows into LDS (coalesced)
    {
        const float4* in4 = (const float4*)(inputs + (size_t)rb * FEAT);
        float4* il4 = (float4*)inlds;
        for (int i = t; i < 16 * FEAT / 4; i += 256) il4[i] = in4[i];
    }
    __syncthreads();

    const int d = t & 63;      // hid dim (also lane id)
    const int wv = t >> 6;     // wave id -> rows wv*4..wv*4+3
    const float asrc = a[d];
    const float adst = a[HID + d];

    float h0 = 0.f, h1 = 0.f, h2 = 0.f, h3 = 0.f;
    const float* wp = W + d;                 // W[k][d], stride HID
    const float* ip = inlds + (wv * 4) * FEAT;
    #pragma unroll 4
    for (int k = 0; k < FEAT; ++k) {
        float wk = wp[(size_t)k * HID];      // coalesced across lanes, L2-hot
        h0 = fmaf(ip[k],            wk, h0); // LDS broadcasts
        h1 = fmaf(ip[FEAT + k],     wk, h1);
        h2 = fmaf(ip[2 * FEAT + k], wk, h2);
        h3 = fmaf(ip[3 * FEAT + k], wk, h3);
    }

    float hv[4] = {h0, h1, h2, h3};
    #pragma unroll
    for (int rr = 0; rr < 4; ++rr) {
        const int row = rb + wv * 4 + rr;
        // wave-wide reductions for s_src / s_dst (fp32 exact-ish)
        float vs = hv[rr] * asrc;
        float vd = hv[rr] * adst;
        #pragma unroll
        for (int mm = 32; mm >= 1; mm >>= 1) {
            vs += __shfl_xor(vs, mm, 64);
            vd += __shfl_xor(vd, mm, 64);
        }
        if (d == 0) { s_src[row] = vs; s_dst[row] = vd; }

        // bf16 h into B-fragment order:
        // value H[j=row][d] -> frag[ks=row>>5][td=d>>4][lane=quad*16+n][v]
        unsigned short hb = f32_to_bf16(hv[rr]);
        const int ks = row >> 5, kk = row & 31, quad = kk >> 3, v = kk & 7;
        const int td = d >> 4, n = d & 15;
        const int lane_ = quad * 16 + n;
        hfrag[(size_t)(((ks * 4 + td) * 64 + lane_) * 8 + v)] = hb;
    }
}

// ---------------------------------------------------------------------------
// Kernel 2: fused masked-softmax-numerator + PV matmul.
// Wave = 16 rows x 1024 j (32 K-steps of MFMA 16x16x32 bf16).
// Block = 4 waves = same 16 rows, 4 consecutive j-subranges; LDS-combine,
// then atomicAdd partial numerators + row-sums into ws.
// grid = 512 rowgroups * 2 jblocks = 1024 blocks (4/CU, 16 waves/CU).
// ---------------------------------------------------------------------------
__global__ __launch_bounds__(256, 4) void k2_main(
    const int* __restrict__ adj,
    const float* __restrict__ s_src, const float* __restrict__ s_dst,
    const unsigned short* __restrict__ hfrag,
    float* __restrict__ acc_g, float* __restrict__ l_acc)
{
    __shared__ float comb[4 * 16 * HID];  // 16 KB
    __shared__ float lcomb[4 * 16];

    const int t = threadIdx.x;
    const int lane = t & 63, wave = t >> 6;
    const int rowgroup = blockIdx.x >> 1, jblock = blockIdx.x & 1;
    const int rb = rowgroup * 16;
    const int jbase = (jblock * 4 + wave) * 1024;
    const int m = lane & 15, quad = lane >> 4;
    const int row = rb + m;

    const float ssrc = s_src[row];
    // upper bound on row max score (lrelu monotonic, s_dst < SBOUND surely)
    const float mt = ssrc + SBOUND;
    const float mi = fmaxf(mt, 0.f) + ALPHA * fminf(mt, 0.f);
    const float mi2 = mi * LOG2E;

    const int4*   adjp = (const int4*)(adj + (size_t)row * N + jbase + quad * 8);
    const float4* sdp  = (const float4*)(s_dst + jbase + quad * 8);
    const short8* bp   = (const short8*)hfrag;
    const int ks0 = jbase >> 5;

    floatx4 acc[4];
    #pragma unroll
    for (int td = 0; td < 4; ++td) acc[td] = (floatx4){0.f, 0.f, 0.f, 0.f};
    float lsum = 0.f;

    for (int s = 0; s < 32; ++s) {
        // adj: 16 rows x one aligned 128B line per K-step (no over-fetch)
        int4   aj0 = adjp[s * 8];
        int4   aj1 = adjp[s * 8 + 1];
        float4 sd0 = sdp[s * 8];       // broadcast (same addr per quad-group)
        float4 sd1 = sdp[s * 8 + 1];
        const int ks = ks0 + s;
        short8 B0 = bp[(ks * 4 + 0) * 64 + lane];  // fully coalesced, L2-hot
        short8 B1 = bp[(ks * 4 + 1) * 64 + lane];
        short8 B2 = bp[(ks * 4 + 2) * 64 + lane];
        short8 B3 = bp[(ks * 4 + 3) * 64 + lane];

        const float sdv[8] = {sd0.x, sd0.y, sd0.z, sd0.w, sd1.x, sd1.y, sd1.z, sd1.w};
        const int   ajv[8] = {aj0.x, aj0.y, aj0.z, aj0.w, aj1.x, aj1.y, aj1.z, aj1.w};
        short8 A;
        #pragma unroll
        for (int v = 0; v < 8; ++v) {
            float tt = ssrc + sdv[v];
            float lr = fmaf(ALPHA, fminf(tt, 0.f), fmaxf(tt, 0.f));  // leaky relu
            float p  = __builtin_amdgcn_exp2f(fmaf(lr, LOG2E, -mi2));
            p = (ajv[v] > 0) ? p : 0.f;
            lsum += p;
            A[v] = (short)f32_to_bf16(p);
        }
        acc[0] = __builtin_amdgcn_mfma_f32_16x16x32_bf16(A, B0, acc[0], 0, 0, 0);
        acc[1] = __builtin_amdgcn_mfma_f32_16x16x32_bf16(A, B1, acc[1], 0, 0, 0);
        acc[2] = __builtin_amdgcn_mfma_f32_16x16x32_bf16(A, B2, acc[2], 0, 0, 0);
        acc[3] = __builtin_amdgcn_mfma_f32_16x16x32_bf16(A, B3, acc[3], 0, 0, 0);
    }

    // C/D layout (verified): col = lane&15, row = quad*4 + reg
    const int n_ = lane & 15;
    #pragma unroll
    for (int td = 0; td < 4; ++td)
        #pragma unroll
        for (int reg = 0; reg < 4; ++reg) {
            int il = quad * 4 + reg;
            comb[wave * (16 * HID) + il * HID + td * 16 + n_] = acc[td][reg];
        }
    // l: lane's partial covers row m (A-row), quad k-slice -> reduce quads
    float ls = lsum;
    ls += __shfl_xor(ls, 16, 64);
    ls += __shfl_xor(ls, 32, 64);
    if (lane < 16) lcomb[wave * 16 + lane] = ls;
    __syncthreads();

    for (int f = t; f < 16 * HID; f += 256) {
        float sv = comb[f] + comb[f + 1024] + comb[f + 2048] + comb[f + 3072];
        int il = f >> 6, dd = f & 63;
        atomicAdd(&acc_g[(size_t)(rb + il) * HID + dd], sv);
    }
    if (t < 16) {
        float lv = lcomb[t] + lcomb[16 + t] + lcomb[32 + t] + lcomb[48 + t];
        atomicAdd(&l_acc[rb + t], lv);
    }
}

// ---------------------------------------------------------------------------
// Kernel 3: out = relu(acc / l). 131072 float4s.
// ---------------------------------------------------------------------------
__global__ __launch_bounds__(256) void k3_final(
    const float* __restrict__ acc_g, const float* __restrict__ l_acc,
    float* __restrict__ out)
{
    const int idx = blockIdx.x * 256 + threadIdx.x;  // float4 index
    float4 v = ((const float4*)acc_g)[idx];
    const int i = (idx * 4) >> 6;  // row (HID=64 -> 16 float4 per row)
    float li = l_acc[i];
    float inv = (li > 0.f) ? 1.0f / li : 0.f;
    float4 o;
    o.x = fmaxf(v.x * inv, 0.f);
    o.y = fmaxf(v.y * inv, 0.f);
    o.z = fmaxf(v.z * inv, 0.f);
    o.w = fmaxf(v.w * inv, 0.f);
    ((float4*)out)[idx] = o;
}

extern "C" void kernel_launch(void* const* d_in, const int* in_sizes, int n_in,
                              void* d_out, int out_size, void* d_ws, size_t ws_size,
                              hipStream_t stream) {
    const float* inputs = (const float*)d_in[0];
    const int*   adj    = (const int*)d_in[1];
    // d_in[2] tree_attention: unused by the reference
    const float* W      = (const float*)d_in[3];
    const float* a      = (const float*)d_in[4];
    float* out = (float*)d_out;

    float* acc_g = (float*)d_ws;                 // N*HID fp32  (2 MB)
    float* l_acc = acc_g + (size_t)N * HID;      // N fp32      (32 KB)
    float* s_src = l_acc + N;                    // N fp32
    float* s_dst = s_src + N;                    // N fp32
    unsigned short* hfrag = (unsigned short*)(s_dst + N);  // N*HID bf16 (1 MB)

    k1_prep<<<512, 256, 0, stream>>>(inputs, W, a, s_src, s_dst, hfrag, acc_g);
    k2_main<<<1024, 256, 0, stream>>>(adj, s_src, s_dst, hfrag, acc_g, l_acc);
    k3_final<<<512, 256, 0, stream>>>(acc_g, l_acc, out);
}

// Round 2
// 531.861 us; speedup vs baseline: 1.0025x; 1.0025x over previous
//
#include <hip/hip_runtime.h>
#include <stdint.h>

#define N 8192
#define FEAT 256
#define HID 64
#define ALPHA 0.2f
#define SBOUND 16.0f
#define LOG2E 1.44269504088896f

typedef __attribute__((ext_vector_type(8))) short short8;
typedef __attribute__((ext_vector_type(4))) float floatx4;

static __device__ __forceinline__ unsigned short f32_to_bf16(float f) {
    union { float f; unsigned int u; } c; c.f = f;
    return (unsigned short)((c.u + 0x8000u) >> 16);  // RN ties-away; p>=0 so fine
}

// ---------------------------------------------------------------------------
// Kernel 1: h = inputs@W (fp32), s_src/s_dst = h@a halves,
// e1 = 2^(s_dst*log2e), e2 = 2^(ALPHA*s_dst*log2e)  (factorized lrelu-exp),
// hfrag = bf16(h) pre-swizzled into MFMA 16x16x32 B-fragment order.
// Also zero-initializes acc_g and l_acc (ws is poisoned 0xAA each call).
// ---------------------------------------------------------------------------
__global__ __launch_bounds__(256) void k1_prep(
    const float* __restrict__ inputs, const float* __restrict__ W,
    const float* __restrict__ a,
    float* __restrict__ s_src, float* __restrict__ s_dst,
    float* __restrict__ e1, float* __restrict__ e2,
    unsigned short* __restrict__ hfrag, float* __restrict__ acc_zero)
{
    __shared__ float inlds[16 * FEAT];  // 16 KB
    const int t = threadIdx.x;
    const int rb = blockIdx.x * 16;

    // zero acc_g (N*HID) + l_acc (N)
    {
        const int totf4 = (N * HID + N) / 4;
        float4 z = make_float4(0.f, 0.f, 0.f, 0.f);
        for (int i = blockIdx.x * 256 + t; i < totf4; i += gridDim.x * 256)
            ((float4*)acc_zero)[i] = z;
    }

    // stage 16 input rows into LDS (coalesced)
    {
        const float4* in4 = (const float4*)(inputs + (size_t)rb * FEAT);
        float4* il4 = (float4*)inlds;
        for (int i = t; i < 16 * FEAT / 4; i += 256) il4[i] = in4[i];
    }
    __syncthreads();

    const int d = t & 63;      // hid dim (== lane id)
    const int wv = t >> 6;     // wave id -> rows wv*4..wv*4+3
    const float asrc = a[d];
    const float adst = a[HID + d];

    float h0 = 0.f, h1 = 0.f, h2 = 0.f, h3 = 0.f;
    const float* wp = W + d;                 // W[k][d], stride HID
    const float* ip = inlds + (wv * 4) * FEAT;
    #pragma unroll 4
    for (int k = 0; k < FEAT; ++k) {
        float wk = wp[(size_t)k * HID];      // coalesced across lanes, L2-hot
        h0 = fmaf(ip[k],            wk, h0); // LDS broadcasts
        h1 = fmaf(ip[FEAT + k],     wk, h1);
        h2 = fmaf(ip[2 * FEAT + k], wk, h2);
        h3 = fmaf(ip[3 * FEAT + k], wk, h3);
    }

    float hv[4] = {h0, h1, h2, h3};
    #pragma unroll
    for (int rr = 0; rr < 4; ++rr) {
        const int row = rb + wv * 4 + rr;
        float vs = hv[rr] * asrc;
        float vd = hv[rr] * adst;
        #pragma unroll
        for (int mm = 32; mm >= 1; mm >>= 1) {
            vs += __shfl_xor(vs, mm, 64);
            vd += __shfl_xor(vd, mm, 64);
        }
        if (d == 0) {
            s_src[row] = vs;
            s_dst[row] = vd;
            e1[row] = __builtin_amdgcn_exp2f(vd * LOG2E);
            e2[row] = __builtin_amdgcn_exp2f(ALPHA * vd * LOG2E);
        }

        // bf16 h into B-fragment order:
        // H[j=row][d] -> frag[ks=row>>5][td=d>>4][lane=quad*16+n][v]
        unsigned short hb = f32_to_bf16(hv[rr]);
        const int ks = row >> 5, kk = row & 31, quad = kk >> 3, v = kk & 7;
        const int td = d >> 4, n = d & 15;
        const int lane_ = quad * 16 + n;
        hfrag[(size_t)(((ks * 4 + td) * 64 + lane_) * 8 + v)] = hb;
    }
}

// ---------------------------------------------------------------------------
// Kernel 2: fused masked-softmax-numerator + PV matmul.
// Wave = 16 rows x 1024 j (32 K-steps of MFMA 16x16x32 bf16).
// s-loop: unroll pinned OFF (unrolling hoists 8+ VMEM/iter -> VGPR spill),
// adj (the only HBM stream) software-prefetched 1 step ahead.
// p = (e1[j] > thrE) ? c1*e1[j] : c2*e2[j]  -- no transcendental per entry.
// ---------------------------------------------------------------------------
__global__ __launch_bounds__(256, 4) void k2_main(
    const int* __restrict__ adj,
    const float* __restrict__ s_src,
    const float* __restrict__ e1, const float* __restrict__ e2,
    const unsigned short* __restrict__ hfrag,
    float* __restrict__ acc_g, float* __restrict__ l_acc)
{
    __shared__ float comb[4 * 16 * HID];  // 16 KB
    __shared__ float lcomb[4 * 16];

    const int t = threadIdx.x;
    const int lane = t & 63, wave = t >> 6;
    const int rowgroup = blockIdx.x >> 1, jblock = blockIdx.x & 1;
    const int rb = rowgroup * 16;
    const int jbase = (jblock * 4 + wave) * 1024;
    const int m = lane & 15, quad = lane >> 4;
    const int row = rb + m;

    const float ssrc = s_src[row];
    // mi = lrelu(upper bound on row max score); keeps p in [0,1]
    const float mt = ssrc + SBOUND;
    const float mi = fmaxf(mt, 0.f) + ALPHA * fminf(mt, 0.f);
    const float c1 = __builtin_amdgcn_exp2f((ssrc - mi) * LOG2E);
    const float c2 = __builtin_amdgcn_exp2f((ALPHA * ssrc - mi) * LOG2E);
    const float thrE = __builtin_amdgcn_exp2f(-ssrc * LOG2E);

    const int4*   adjp = (const int4*)(adj + (size_t)row * N + jbase + quad * 8);
    const float4* e1p  = (const float4*)(e1 + jbase + quad * 8);
    const float4* e2p  = (const float4*)(e2 + jbase + quad * 8);
    const short8* bp   = (const short8*)hfrag;
    const int ks0 = jbase >> 5;

    floatx4 acc[4];
    #pragma unroll
    for (int td = 0; td < 4; ++td) acc[td] = (floatx4){0.f, 0.f, 0.f, 0.f};
    float lsum = 0.f;

    // prefetch s=0 adj
    int4 naj0 = adjp[0];
    int4 naj1 = adjp[1];

    #pragma clang loop unroll(disable)
    for (int s = 0; s < 32; ++s) {
        const int4 aj0 = naj0, aj1 = naj1;
        const int sn = (s < 31) ? s + 1 : 31;
        naj0 = adjp[sn * 8];           // HBM stream: 16 rows x one 128B line
        naj1 = adjp[sn * 8 + 1];
        float4 e1a = e1p[s * 8], e1b = e1p[s * 8 + 1];   // broadcast, L2-hot
        float4 e2a = e2p[s * 8], e2b = e2p[s * 8 + 1];
        const int ks = ks0 + s;
        short8 B0 = bp[(ks * 4 + 0) * 64 + lane];        // coalesced, L2-hot
        short8 B1 = bp[(ks * 4 + 1) * 64 + lane];
        short8 B2 = bp[(ks * 4 + 2) * 64 + lane];
        short8 B3 = bp[(ks * 4 + 3) * 64 + lane];

        const float e1v[8] = {e1a.x, e1a.y, e1a.z, e1a.w, e1b.x, e1b.y, e1b.z, e1b.w};
        const float e2v[8] = {e2a.x, e2a.y, e2a.z, e2a.w, e2b.x, e2b.y, e2b.z, e2b.w};
        const int   ajv[8] = {aj0.x, aj0.y, aj0.z, aj0.w, aj1.x, aj1.y, aj1.z, aj1.w};
        short8 A;
        #pragma unroll
        for (int v = 0; v < 8; ++v) {
            const bool pos = e1v[v] > thrE;              // == (ssrc+sdst_j > 0)
            float f = pos ? e1v[v] : e2v[v];
            float c = pos ? c1 : c2;
            float p = f * c;
            p = (ajv[v] > 0) ? p : 0.f;
            lsum += p;
            A[v] = (short)f32_to_bf16(p);
        }
        acc[0] = __builtin_amdgcn_mfma_f32_16x16x32_bf16(A, B0, acc[0], 0, 0, 0);
        acc[1] = __builtin_amdgcn_mfma_f32_16x16x32_bf16(A, B1, acc[1], 0, 0, 0);
        acc[2] = __builtin_amdgcn_mfma_f32_16x16x32_bf16(A, B2, acc[2], 0, 0, 0);
        acc[3] = __builtin_amdgcn_mfma_f32_16x16x32_bf16(A, B3, acc[3], 0, 0, 0);
    }

    // C/D layout: col = lane&15, row = quad*4 + reg
    const int n_ = lane & 15;
    #pragma unroll
    for (int td = 0; td < 4; ++td)
        #pragma unroll
        for (int reg = 0; reg < 4; ++reg) {
            int il = quad * 4 + reg;
            comb[wave * (16 * HID) + il * HID + td * 16 + n_] = acc[td][reg];
        }
    float ls = lsum;
    ls += __shfl_xor(ls, 16, 64);
    ls += __shfl_xor(ls, 32, 64);
    if (lane < 16) lcomb[wave * 16 + lane] = ls;
    __syncthreads();

    for (int f = t; f < 16 * HID; f += 256) {
        float sv = comb[f] + comb[f + 1024] + comb[f + 2048] + comb[f + 3072];
        int il = f >> 6, dd = f & 63;
        atomicAdd(&acc_g[(size_t)(rb + il) * HID + dd], sv);
    }
    if (t < 16) {
        float lv = lcomb[t] + lcomb[16 + t] + lcomb[32 + t] + lcomb[48 + t];
        atomicAdd(&l_acc[rb + t], lv);
    }
}

// ---------------------------------------------------------------------------
// Kernel 3: out = relu(acc / l).
// ---------------------------------------------------------------------------
__global__ __launch_bounds__(256) void k3_final(
    const float* __restrict__ acc_g, const float* __restrict__ l_acc,
    float* __restrict__ out)
{
    const int idx = blockIdx.x * 256 + threadIdx.x;  // float4 index
    float4 v = ((const float4*)acc_g)[idx];
    const int i = (idx * 4) >> 6;  // row
    float li = l_acc[i];
    float inv = (li > 0.f) ? 1.0f / li : 0.f;
    float4 o;
    o.x = fmaxf(v.x * inv, 0.f);
    o.y = fmaxf(v.y * inv, 0.f);
    o.z = fmaxf(v.z * inv, 0.f);
    o.w = fmaxf(v.w * inv, 0.f);
    ((float4*)out)[idx] = o;
}

extern "C" void kernel_launch(void* const* d_in, const int* in_sizes, int n_in,
                              void* d_out, int out_size, void* d_ws, size_t ws_size,
                              hipStream_t stream) {
    const float* inputs = (const float*)d_in[0];
    const int*   adj    = (const int*)d_in[1];
    // d_in[2] tree_attention: unused by the reference
    const float* W      = (const float*)d_in[3];
    const float* a      = (const float*)d_in[4];
    float* out = (float*)d_out;

    float* acc_g = (float*)d_ws;                 // N*HID fp32  (2 MB)
    float* l_acc = acc_g + (size_t)N * HID;      // N fp32
    float* s_src = l_acc + N;                    // N fp32
    float* s_dst = s_src + N;                    // N fp32
    unsigned short* hfrag = (unsigned short*)(s_dst + N);  // N*HID bf16 (1 MB)
    float* e1 = (float*)(hfrag + (size_t)N * HID);         // N fp32
    float* e2 = e1 + N;                                    // N fp32

    k1_prep<<<512, 256, 0, stream>>>(inputs, W, a, s_src, s_dst, e1, e2, hfrag, acc_g);
    k2_main<<<1024, 256, 0, stream>>>(adj, s_src, e1, e2, hfrag, acc_g, l_acc);
    k3_final<<<512, 256, 0, stream>>>(acc_g, l_acc, out);
}